// Round 16
// baseline (387.115 us; speedup 1.0000x reference)
//
#include <hip/hip_runtime.h>
#include <hip/hip_bf16.h>

#define N_NODES 100000
#define N_EDGES 1200000
#define G_GRAPHS 128
#define CAP 64      // max in-degree capacity (Poisson mean 12; max deg @1e-10 ~ 40)
#define AP 68       // A row stride (floats): 272B = 17*16B, keeps b128 aligned
#define SLICE_N 12500   // N_NODES / 8 XCDs

// bf16 helpers: RTN pack, shift/mask unpack (hi element needs only a mask)
__device__ __forceinline__ ushort f2bf(float f) {
    uint u = __float_as_uint(f);
    return (ushort)((u + 0x7FFF + ((u >> 16) & 1)) >> 16);
}
__device__ __forceinline__ uint pack2(float a, float b) {
    return (uint)f2bf(a) | ((uint)f2bf(b) << 16);
}
// unpack uint2 (4 bf16) -> float4
__device__ __forceinline__ float4 bf4(uint2 w) {
    float4 r;
    r.x = __uint_as_float(w.x << 16);
    r.y = __uint_as_float(w.x & 0xFFFF0000u);
    r.z = __uint_as_float(w.y << 16);
    r.w = __uint_as_float(w.y & 0xFFFF0000u);
    return r;
}

// ---------------- CSR build (by dst), XCD-sliced (R11: 72->57MB writes) ------
__global__ void scatter_k(const int* __restrict__ ei, int* __restrict__ cnt,
                          int* __restrict__ adj) {
    int slice = blockIdx.x & 7;
    int e = (blockIdx.x >> 3) * 256 + threadIdx.x;
    if (e >= N_EDGES) return;
    int s = ei[e];             // src
    int d = ei[N_EDGES + e];   // dst
    s = min(max(s, 0), N_NODES - 1);
    d = min(max(d, 0), N_NODES - 1);
    if (d / SLICE_N != slice) return;    // another XCD's dst range
    int pos = atomicAdd(&cnt[d], 1);
    if (pos < CAP) adj[d * CAP + pos] = s;
}

// ---------------- embedding gather -> bf16 h; also zero cnt + sentinels ------
__global__ void embed_k(const int* __restrict__ x, const float4* __restrict__ emb,
                        ushort* __restrict__ hbfA, ushort* __restrict__ hbfB,
                        int* __restrict__ cnt) {
    int t = blockIdx.x * 256 + threadIdx.x;
    if (t > N_NODES * 16 + 15) return;
    int n = t >> 4, q = t & 15;
    if (t < N_NODES) cnt[t] = 0;                    // fold memset
    if (n < N_NODES) {
        float4 v = emb[x[n] * 16 + q];
        *(uint2*)(hbfA + n * 64 + q * 4) = make_uint2(pack2(v.x, v.y), pack2(v.z, v.w));
    } else {                                        // sentinel rows = 0
        *(uint2*)(hbfA + n * 64 + q * 4) = make_uint2(0u, 0u);
        *(uint2*)(hbfB + n * 64 + q * 4) = make_uint2(0u, 0u);
    }
}

__device__ __forceinline__ void f4add(float4& a, const float4 b) {
    a.x += b.x; a.y += b.y; a.z += b.z; a.w += b.w;
}

__device__ __forceinline__ float elu(float v) { return v > 0.f ? v : expm1f(v); }

// 64x64x64 micro-tiled matmul, A row-major [node][k] stride AP (conflict-free).
// R12 lesson: one wv live at a time, unroll 2 -> ~45 VGPR live set.
#define FMA16(comp, wv)                                                        \
    acc[0][0] += av0.comp * wv.x; acc[0][1] += av0.comp * wv.y;                \
    acc[0][2] += av0.comp * wv.z; acc[0][3] += av0.comp * wv.w;                \
    acc[1][0] += av1.comp * wv.x; acc[1][1] += av1.comp * wv.y;                \
    acc[1][2] += av1.comp * wv.z; acc[1][3] += av1.comp * wv.w;                \
    acc[2][0] += av2.comp * wv.x; acc[2][1] += av2.comp * wv.y;                \
    acc[2][2] += av2.comp * wv.z; acc[2][3] += av2.comp * wv.w;                \
    acc[3][0] += av3.comp * wv.x; acc[3][1] += av3.comp * wv.y;                \
    acc[3][2] += av3.comp * wv.z; acc[3][3] += av3.comp * wv.w;

__device__ __forceinline__ void mm64(const float* __restrict__ A,
                                     const float* __restrict__ Ws,
                                     float acc[4][4], int tr, int tc) {
    #pragma unroll 2
    for (int k4 = 0; k4 < 16; ++k4) {
        float4 av0 = *(const float4*)(A + (tr * 4 + 0) * AP + k4 * 4);
        float4 av1 = *(const float4*)(A + (tr * 4 + 1) * AP + k4 * 4);
        float4 av2 = *(const float4*)(A + (tr * 4 + 2) * AP + k4 * 4);
        float4 av3 = *(const float4*)(A + (tr * 4 + 3) * AP + k4 * 4);
        {
            float4 wv = *(const float4*)(Ws + (k4 * 4 + 0) * 64 + tc * 4);
            FMA16(x, wv)
        }
        {
            float4 wv = *(const float4*)(Ws + (k4 * 4 + 1) * 64 + tc * 4);
            FMA16(y, wv)
        }
        {
            float4 wv = *(const float4*)(Ws + (k4 * 4 + 2) * 64 + tc * 4);
            FMA16(z, wv)
        }
        {
            float4 wv = *(const float4*)(Ws + (k4 * 4 + 3) * 64 + tc * 4);
            FMA16(w, wv)
        }
    }
}

// per-iteration gather step for one row: 2 adj int4 reads (always in-bounds of
// the CAP row), 8 masked bf16-row loads, 8 accumulates into A.
#define GATHER8(A, ap, dg, base, q)                                            \
    {                                                                          \
        int4 sa = (ap)[2 * gi];                                                \
        int4 sb = (ap)[2 * gi + 1];                                            \
        int t0 = ((base) + 0 < (dg)) ? sa.x : N_NODES;                         \
        int t1 = ((base) + 1 < (dg)) ? sa.y : N_NODES;                         \
        int t2 = ((base) + 2 < (dg)) ? sa.z : N_NODES;                         \
        int t3 = ((base) + 3 < (dg)) ? sa.w : N_NODES;                         \
        int t4 = ((base) + 4 < (dg)) ? sb.x : N_NODES;                         \
        int t5 = ((base) + 5 < (dg)) ? sb.y : N_NODES;                         \
        int t6 = ((base) + 6 < (dg)) ? sb.z : N_NODES;                         \
        int t7 = ((base) + 7 < (dg)) ? sb.w : N_NODES;                         \
        uint2 u0 = *(const uint2*)(hin + t0 * 64 + (q) * 4);                   \
        uint2 u1 = *(const uint2*)(hin + t1 * 64 + (q) * 4);                   \
        uint2 u2 = *(const uint2*)(hin + t2 * 64 + (q) * 4);                   \
        uint2 u3 = *(const uint2*)(hin + t3 * 64 + (q) * 4);                   \
        uint2 u4 = *(const uint2*)(hin + t4 * 64 + (q) * 4);                   \
        uint2 u5 = *(const uint2*)(hin + t5 * 64 + (q) * 4);                   \
        uint2 u6 = *(const uint2*)(hin + t6 * 64 + (q) * 4);                   \
        uint2 u7 = *(const uint2*)(hin + t7 * 64 + (q) * 4);                   \
        f4add(A, bf4(u0)); f4add(A, bf4(u1)); f4add(A, bf4(u2));               \
        f4add(A, bf4(u3)); f4add(A, bf4(u4)); f4add(A, bf4(u5));               \
        f4add(A, bf4(u6)); f4add(A, bf4(u7));                                  \
    }

// ------ fused GIN layer: hout <- elu(W2^T(elu(BN(W1^T(self+neigh)))) + b2) ----
// R15 lesson: per-row dynamic gather loops serialize the 4 staged rows (each
// lane ~8 loads in flight, VGPR 52/128). Here all 4 rows share a UNIFORM trip
// count (max g8) with per-element sentinel masking -> up to 32 loads in
// flight per lane, cross-row ILP hides L3 latency.
__global__ void __launch_bounds__(256, 4) mlp_k(const ushort* __restrict__ hin,
    ushort* __restrict__ hout, const int* __restrict__ adj,
    const int* __restrict__ cnt,
    const float* __restrict__ W1, const float* __restrict__ b1,
    const float* __restrict__ g,  const float* __restrict__ be,
    const float* __restrict__ W2, const float* __restrict__ b2) {
    __shared__ float At[64 * AP];     // A row-major [node][k]; reused for y
    __shared__ float Wbuf[4096];      // W1 for mm1, then W2 for mm2
    __shared__ float sc1[64], ep1[64], ep2[64];
    int tid = threadIdx.x;
    int n0 = blockIdx.x * 64;

    for (int idx = tid; idx < 1024; idx += 256)
        ((float4*)Wbuf)[idx] = ((const float4*)W1)[idx];
    if (tid < 64) {
        const float inv = rsqrtf(1.0f + 1e-5f);
        float s = g[tid] * inv;
        sc1[tid] = s;
        ep1[tid] = b1[tid] * s + be[tid];
        ep2[tid] = b2[tid];
    }
    {   // stage: At[node][k] = h[self] + sum_neighbors h[s], 4 rows interleaved
        int r = tid >> 4, q = tid & 15;
        int nr0 = n0 + 0 * 16 + r, nr1 = n0 + 1 * 16 + r;
        int nr2 = n0 + 2 * 16 + r, nr3 = n0 + 3 * 16 + r;
        // OOB rows -> sentinel (deg 0, self = zero row)
        int m0 = (nr0 < N_NODES) ? nr0 : N_NODES;
        int m1 = (nr1 < N_NODES) ? nr1 : N_NODES;
        int m2 = (nr2 < N_NODES) ? nr2 : N_NODES;
        int m3 = (nr3 < N_NODES) ? nr3 : N_NODES;
        int d0 = (m0 < N_NODES) ? min(cnt[m0], CAP) : 0;
        int d1 = (m1 < N_NODES) ? min(cnt[m1], CAP) : 0;
        int d2 = (m2 < N_NODES) ? min(cnt[m2], CAP) : 0;
        int d3 = (m3 < N_NODES) ? min(cnt[m3], CAP) : 0;
        const int4* p0 = (const int4*)(adj + m0 * CAP);   // sentinel row m=N_NODES
        const int4* p1 = (const int4*)(adj + m1 * CAP);   // never dereferenced OOB:
        const int4* p2 = (const int4*)(adj + m2 * CAP);   // gi<gmax=0 when all deg 0
        const int4* p3 = (const int4*)(adj + m3 * CAP);
        float4 A0 = bf4(*(const uint2*)(hin + m0 * 64 + q * 4));  // self terms
        float4 A1 = bf4(*(const uint2*)(hin + m1 * 64 + q * 4));
        float4 A2 = bf4(*(const uint2*)(hin + m2 * 64 + q * 4));
        float4 A3 = bf4(*(const uint2*)(hin + m3 * 64 + q * 4));
        int gmax = (max(max(d0, d1), max(d2, d3)) + 7) >> 3;
        for (int gi = 0; gi < gmax; ++gi) {
            int base = gi * 8;
            GATHER8(A0, p0, d0, base, q)
            GATHER8(A1, p1, d1, base, q)
            GATHER8(A2, p2, d2, base, q)
            GATHER8(A3, p3, d3, base, q)
        }
        *(float4*)(At + (0 * 16 + r) * AP + q * 4) = A0;  // lane-consecutive
        *(float4*)(At + (1 * 16 + r) * AP + q * 4) = A1;
        *(float4*)(At + (2 * 16 + r) * AP + q * 4) = A2;
        *(float4*)(At + (3 * 16 + r) * AP + q * 4) = A3;
    }
    __syncthreads();

    int tr = tid >> 4, tc = tid & 15;
    float acc[4][4];
    #pragma unroll
    for (int e = 0; e < 4; ++e)
        #pragma unroll
        for (int j = 0; j < 4; ++j) acc[e][j] = 0.f;

    mm64(At, Wbuf, acc, tr, tc);
    __syncthreads();                   // all waves done reading At and Wbuf(W1)
    // epilogue 1 (y into At) + stage W2 into Wbuf, then one barrier
    #pragma unroll
    for (int e = 0; e < 4; ++e) {
        float4 o;
        o.x = elu(acc[e][0] * sc1[tc * 4 + 0] + ep1[tc * 4 + 0]);
        o.y = elu(acc[e][1] * sc1[tc * 4 + 1] + ep1[tc * 4 + 1]);
        o.z = elu(acc[e][2] * sc1[tc * 4 + 2] + ep1[tc * 4 + 2]);
        o.w = elu(acc[e][3] * sc1[tc * 4 + 3] + ep1[tc * 4 + 3]);
        *(float4*)(At + (tr * 4 + e) * AP + tc * 4) = o;   // lane-consecutive
    }
    for (int idx = tid; idx < 1024; idx += 256)
        ((float4*)Wbuf)[idx] = ((const float4*)W2)[idx];
    __syncthreads();
    #pragma unroll
    for (int e = 0; e < 4; ++e)
        #pragma unroll
        for (int j = 0; j < 4; ++j) acc[e][j] = 0.f;

    mm64(At, Wbuf, acc, tr, tc);
    #pragma unroll
    for (int e = 0; e < 4; ++e) {      // epilogue 2: +b2, outer elu, bf16 store
        int n = n0 + tr * 4 + e;
        if (n < N_NODES) {
            float o0 = elu(acc[e][0] + ep2[tc * 4 + 0]);
            float o1 = elu(acc[e][1] + ep2[tc * 4 + 1]);
            float o2 = elu(acc[e][2] + ep2[tc * 4 + 2]);
            float o3 = elu(acc[e][3] + ep2[tc * 4 + 3]);
            *(uint2*)(hout + n * 64 + tc * 4) = make_uint2(pack2(o0, o1), pack2(o2, o3));
        }
    }
}

// ---------------- mean pool per graph (batch sorted -> binary search bounds) ----
__global__ void pool_k(const ushort* __restrict__ h, const int* __restrict__ batch,
                       float4* __restrict__ pooled) {
    int gph = blockIdx.x;
    int tid = threadIdx.x;          // 256
    int lo = 0, hi = N_NODES;
    while (lo < hi) { int mid = (lo + hi) >> 1; if (batch[mid] < gph) lo = mid + 1; else hi = mid; }
    int start = lo;
    hi = N_NODES;
    while (lo < hi) { int mid = (lo + hi) >> 1; if (batch[mid] < gph + 1) lo = mid + 1; else hi = mid; }
    int end = lo;
    int q = tid & 15, r = tid >> 4;
    float4 acc = make_float4(0.f, 0.f, 0.f, 0.f);
    for (int n = start + r; n < end; n += 16)
        f4add(acc, bf4(*(const uint2*)(h + n * 64 + q * 4)));
    __shared__ float4 red[256];
    red[tid] = acc;
    __syncthreads();
    for (int s = 8; s > 0; s >>= 1) {
        if (r < s) {
            float4 o = red[(r + s) * 16 + q];
            float4 m = red[r * 16 + q];
            m.x += o.x; m.y += o.y; m.z += o.z; m.w += o.w;
            red[r * 16 + q] = m;
        }
        __syncthreads();
    }
    if (r == 0) {
        float invc = 1.0f / fmaxf((float)(end - start), 1.0f);
        float4 m = red[q];
        m.x *= invc; m.y *= invc; m.z *= invc; m.w *= invc;
        pooled[gph * 16 + q] = m;
    }
}

// ---------------- readout head: one wave per graph, lane j owns output j ------
__global__ void __launch_bounds__(256) head_k(const float* __restrict__ pooled,
    const float* __restrict__ Wr1, const float* __restrict__ br1,
    const float* __restrict__ Wr2, const float* __restrict__ br2,
    const float* __restrict__ Wo,  const float* __restrict__ bo,
    float* __restrict__ out) {
    __shared__ float ylds[4][64];
    int wid = threadIdx.x >> 6, j = threadIdx.x & 63;
    int gph = blockIdx.x * 4 + wid;   // 32 blocks x 4 waves = 128 graphs
    float acc = 0.f;
    #pragma unroll 8
    for (int k = 0; k < 64; ++k)
        acc += pooled[gph * 64 + k] * Wr1[k * 64 + j];   // bcast * coalesced
    float yv = acc + br1[j];
    ylds[wid][j] = elu(yv);
    __syncthreads();
    float acc2 = 0.f;
    #pragma unroll 8
    for (int k = 0; k < 64; ++k)
        acc2 += ylds[wid][k] * Wr2[k * 64 + j];
    float p = (acc2 + br2[j]) * Wo[j];
    #pragma unroll
    for (int off = 32; off > 0; off >>= 1) p += __shfl_down(p, off);
    if (j == 0) out[gph] = bo[0] + p;
}

extern "C" void kernel_launch(void* const* d_in, const int* in_sizes, int n_in,
                              void* d_out, int out_size, void* d_ws, size_t ws_size,
                              hipStream_t stream) {
    const int*   x     = (const int*)d_in[0];
    const int*   ei    = (const int*)d_in[1];
    const int*   batch = (const int*)d_in[2];
    const float* emb   = (const float*)d_in[3];
    const float* P[24];
    for (int i = 0; i < 24; ++i) P[i] = (const float*)d_in[4 + i];

    char* ws = (char*)d_ws;
    ushort* hbfA  = (ushort*)(ws + 0);          // (N+1)*64 bf16 = 12.81 MB
    ushort* hbfB  = (ushort*)(ws + 13000000);   // 12.81 MB
    int*    adj   = (int*)   (ws + 26000000);   // 25.6 MB ((N+1)*CAP; sentinel row unread)
    int*    cnt   = (int*)   (ws + 52000000);   // 0.4 MB
    float*  pooled= (float*) (ws + 52500000);   // 32 KB

    // embed first: zeroes cnt + both sentinel rows (no memsets, fewer dispatches)
    embed_k<<<(N_NODES * 16 + 16 + 255) / 256, 256, 0, stream>>>(
        x, (const float4*)emb, hbfA, hbfB, cnt);
    scatter_k<<<8 * ((N_EDGES + 255) / 256), 256, 0, stream>>>(ei, cnt, adj);
    // ping-pong: L0 hbfA->hbfB, L1 hbfB->hbfA, L2 hbfA->hbfB
    for (int L = 0; L < 3; ++L) {
        const float* const* p = P + 6 * L;
        const ushort* hin = (L & 1) ? hbfB : hbfA;
        ushort* hout      = (L & 1) ? hbfA : hbfB;
        mlp_k<<<(N_NODES + 63) / 64, 256, 0, stream>>>(
            hin, hout, adj, cnt, p[0], p[1], p[2], p[3], p[4], p[5]);
    }
    pool_k<<<G_GRAPHS, 256, 0, stream>>>(hbfB, batch, (float4*)pooled);
    head_k<<<32, 256, 0, stream>>>(pooled, P[18], P[19], P[20], P[21], P[22], P[23],
                                   (float*)d_out);
}